// Round 1
// baseline (1203.840 us; speedup 1.0000x reference)
//
#include <hip/hip_runtime.h>
#include <math.h>

#define B_    2
#define L_    2048
#define D_    1024
#define H_    16
#define HD_   64
#define HALF_ 128
#define TQ    16
#define WMAX  272   // max band width for a 16-query tile: 256 + 16

// ---------------------------------------------------------------------------
// fp32 tiled GEMM with bias: C[M,N] = A[M,K] @ B[K,N] + bias[N]
// BM=BN=64, BK=16, 256 threads, 4x4 microtile per thread.
// M,N,K assumed divisible by tile dims (true for all our shapes).
// ---------------------------------------------------------------------------
template <int BM, int BN, int BK>
__global__ __launch_bounds__(256) void sgemm_bias(const float* __restrict__ A,
                                                  const float* __restrict__ Bm,
                                                  const float* __restrict__ bias,
                                                  float* __restrict__ C,
                                                  int M, int N, int K) {
  __shared__ float As[BK][BM + 4];  // +4 pad keeps float4 alignment, shifts banks
  __shared__ float Bs[BK][BN];

  const int tx  = threadIdx.x;      // 0..15
  const int ty  = threadIdx.y;      // 0..15
  const int tid = ty * 16 + tx;
  const int row0 = blockIdx.y * BM;
  const int col0 = blockIdx.x * BN;

  float acc[4][4] = {};

  const int aRow = tid >> 2;          // 0..63
  const int aCol = (tid & 3) << 2;    // 0,4,8,12
  const int bRow = tid >> 4;          // 0..15
  const int bCol = (tid & 15) << 2;   // 0..60

  for (int k0 = 0; k0 < K; k0 += BK) {
    const float4 av = *(const float4*)&A[(size_t)(row0 + aRow) * K + k0 + aCol];
    const float4 bv = *(const float4*)&Bm[(size_t)(k0 + bRow) * N + col0 + bCol];
    As[aCol + 0][aRow] = av.x;
    As[aCol + 1][aRow] = av.y;
    As[aCol + 2][aRow] = av.z;
    As[aCol + 3][aRow] = av.w;
    *(float4*)&Bs[bRow][bCol] = bv;
    __syncthreads();

#pragma unroll
    for (int k = 0; k < BK; ++k) {
      const float4 a4 = *(const float4*)&As[k][ty * 4];
      const float4 b4 = *(const float4*)&Bs[k][tx * 4];
      const float a[4] = {a4.x, a4.y, a4.z, a4.w};
      const float b[4] = {b4.x, b4.y, b4.z, b4.w};
#pragma unroll
      for (int i = 0; i < 4; ++i)
#pragma unroll
        for (int j = 0; j < 4; ++j)
          acc[i][j] = fmaf(a[i], b[j], acc[i][j]);
    }
    __syncthreads();
  }

  const float4 bb = *(const float4*)&bias[col0 + tx * 4];
#pragma unroll
  for (int i = 0; i < 4; ++i) {
    float4 o;
    o.x = acc[i][0] + bb.x;
    o.y = acc[i][1] + bb.y;
    o.z = acc[i][2] + bb.z;
    o.w = acc[i][3] + bb.w;
    *(float4*)&C[(size_t)(row0 + ty * 4 + i) * N + col0 + tx * 4] = o;
  }
}

// ---------------------------------------------------------------------------
// Sliding-window attention.
// qkv layout: [B, L, 3, H, HD] (exactly the reference reshape).
// out layout: [B, L, H*HD] = [B, L, D]  (heads concatenated -> next GEMM is plain)
// One block (256 thr) per (b, h, 16-query tile). Band |i-j| <= 128.
// ---------------------------------------------------------------------------
__global__ __launch_bounds__(256) void win_attn(const float* __restrict__ qkv,
                                                float* __restrict__ out) {
  const int b   = blockIdx.z;
  const int h   = blockIdx.y;
  const int i0  = blockIdx.x * TQ;
  const int tid = threadIdx.x;

  const int jlo = max(0, i0 - HALF_);
  const int jhi = min(L_, i0 + TQ + HALF_);
  const int W   = jhi - jlo;  // <= 272

  __shared__ float Qs[TQ][HD_];
  __shared__ float S[TQ][WMAX];
  __shared__ float red[TQ][16];
  __shared__ float rowmax[TQ];
  __shared__ float rowsum[TQ];

  // ---- load Q tile (16 x 64 floats, one float4 per thread)
  {
    const int q = tid >> 4;          // 0..15
    const int d = (tid & 15) << 2;   // 0..60
    const float* src =
        &qkv[(((size_t)(b * L_ + i0 + q) * 3 + 0) * D_) + h * HD_ + d];
    *(float4*)&Qs[q][d] = *(const float4*)src;
  }
  __syncthreads();

  const float scale = 0.125f;  // 1/sqrt(64)

  // ---- scores: 16 x 272 slab, 17 dots of length 64 per thread
  for (int p = tid; p < TQ * WMAX; p += 256) {
    const int q    = p / WMAX;
    const int jrel = p - q * WMAX;
    const int i    = i0 + q;
    const int j    = jlo + jrel;
    float s = -INFINITY;
    const int dij = i - j;
    if (j < jhi && dij >= -HALF_ && dij <= HALF_) {
      const float* kp =
          &qkv[(((size_t)(b * L_ + j) * 3 + 1) * D_) + h * HD_];
      float dot = 0.f;
#pragma unroll
      for (int d4 = 0; d4 < HD_; d4 += 4) {
        const float4 kv = *(const float4*)&kp[d4];
        dot = fmaf(Qs[q][d4 + 0], kv.x, dot);
        dot = fmaf(Qs[q][d4 + 1], kv.y, dot);
        dot = fmaf(Qs[q][d4 + 2], kv.z, dot);
        dot = fmaf(Qs[q][d4 + 3], kv.w, dot);
      }
      s = dot * scale;
    }
    S[q][jrel] = s;
  }
  __syncthreads();

  // ---- softmax per row (16 threads per row); keep exp unnormalized + rowsum
  {
    const int r = tid >> 4;
    const int l = tid & 15;
    float m = -INFINITY;
    for (int jrel = l; jrel < WMAX; jrel += 16) m = fmaxf(m, S[r][jrel]);
    red[r][l] = m;
    __syncthreads();
    if (l == 0) {
      float mm = red[r][0];
#pragma unroll
      for (int u = 1; u < 16; ++u) mm = fmaxf(mm, red[r][u]);
      rowmax[r] = mm;
    }
    __syncthreads();
    const float mrow = rowmax[r];
    float sum = 0.f;
    for (int jrel = l; jrel < WMAX; jrel += 16) {
      const float e = __expf(S[r][jrel] - mrow);  // exp(-inf)=0 handles mask
      S[r][jrel] = e;
      sum += e;
    }
    red[r][l] = sum;
    __syncthreads();
    if (l == 0) {
      float ss = 0.f;
#pragma unroll
      for (int u = 0; u < 16; ++u) ss += red[r][u];
      rowsum[r] = ss;
    }
    __syncthreads();
  }

  // ---- PV: thread -> (d = tid&63, 4 query rows). V loads coalesced in d.
  {
    const int d  = tid & 63;
    const int qg = tid >> 6;  // 0..3
    float acc[4] = {0.f, 0.f, 0.f, 0.f};
    for (int jrel = 0; jrel < W; ++jrel) {
      const int j = jlo + jrel;
      const float v =
          qkv[(((size_t)(b * L_ + j) * 3 + 2) * D_) + h * HD_ + d];
#pragma unroll
      for (int u = 0; u < 4; ++u)
        acc[u] = fmaf(S[qg * 4 + u][jrel], v, acc[u]);
    }
#pragma unroll
    for (int u = 0; u < 4; ++u) {
      const int q = qg * 4 + u;
      out[((size_t)(b * L_ + i0 + q)) * D_ + h * HD_ + d] = acc[u] / rowsum[q];
    }
  }
}

// ---------------------------------------------------------------------------
extern "C" void kernel_launch(void* const* d_in, const int* in_sizes, int n_in,
                              void* d_out, int out_size, void* d_ws, size_t ws_size,
                              hipStream_t stream) {
  const float* x     = (const float*)d_in[0];
  const float* w_qkv = (const float*)d_in[1];
  const float* b_qkv = (const float*)d_in[2];
  const float* w_out = (const float*)d_in[3];
  const float* b_out = (const float*)d_in[4];
  float* out = (float*)d_out;

  // workspace: qkv [B,L,3,H,HD] (50.3 MB) + attn_out [B,L,D] (16.8 MB) = 64 MB
  float* qkv  = (float*)d_ws;
  float* attn = qkv + (size_t)B_ * L_ * 3 * D_;

  const int M = B_ * L_;  // 4096

  {  // QKV projection: [4096,1024] @ [1024,3072] + b_qkv
    dim3 grid(3 * D_ / 64, M / 64), block(16, 16);
    sgemm_bias<64, 64, 16><<<grid, block, 0, stream>>>(x, w_qkv, b_qkv, qkv,
                                                       M, 3 * D_, D_);
  }
  {  // banded attention
    dim3 grid(L_ / TQ, H_, B_), block(256);
    win_attn<<<grid, block, 0, stream>>>(qkv, attn);
  }
  {  // output projection: [4096,1024] @ [1024,1024] + b_out
    dim3 grid(D_ / 64, M / 64), block(16, 16);
    sgemm_bias<64, 64, 16><<<grid, block, 0, stream>>>(attn, w_out, b_out, out,
                                                       M, D_, D_);
  }
}

// Round 2
// 703.610 us; speedup vs baseline: 1.7109x; 1.7109x over previous
//
#include <hip/hip_runtime.h>
#include <math.h>

#define B_    2
#define L_    2048
#define D_    1024
#define H_    16
#define HD_   64
#define HALF_ 128
#define TQ    32          // queries per block
#define CH    32          // keys per staged chunk
#define NCH   9           // chunks: 9*32 = 288 = window(256)+TQ(32)
#define WTOT  (CH * NCH)  // 288
#define KVS   (HD_ + 4)   // 68-float stride for K/V chunk (pad kills write conflicts)
#define STS   (TQ + 2)    // 34-float stride for score slab

// ---------------------------------------------------------------------------
// fp32 tiled GEMM with bias: C[M,N] = A[M,K] @ B[K,N] + bias[N]   (unchanged)
// ---------------------------------------------------------------------------
template <int BM, int BN, int BK>
__global__ __launch_bounds__(256) void sgemm_bias(const float* __restrict__ A,
                                                  const float* __restrict__ Bm,
                                                  const float* __restrict__ bias,
                                                  float* __restrict__ C,
                                                  int M, int N, int K) {
  __shared__ float As[BK][BM + 4];
  __shared__ float Bs[BK][BN];

  const int tx  = threadIdx.x;
  const int ty  = threadIdx.y;
  const int tid = ty * 16 + tx;
  const int row0 = blockIdx.y * BM;
  const int col0 = blockIdx.x * BN;

  float acc[4][4] = {};

  const int aRow = tid >> 2;
  const int aCol = (tid & 3) << 2;
  const int bRow = tid >> 4;
  const int bCol = (tid & 15) << 2;

  for (int k0 = 0; k0 < K; k0 += BK) {
    const float4 av = *(const float4*)&A[(size_t)(row0 + aRow) * K + k0 + aCol];
    const float4 bv = *(const float4*)&Bm[(size_t)(k0 + bRow) * N + col0 + bCol];
    As[aCol + 0][aRow] = av.x;
    As[aCol + 1][aRow] = av.y;
    As[aCol + 2][aRow] = av.z;
    As[aCol + 3][aRow] = av.w;
    *(float4*)&Bs[bRow][bCol] = bv;
    __syncthreads();

#pragma unroll
    for (int k = 0; k < BK; ++k) {
      const float4 a4 = *(const float4*)&As[k][ty * 4];
      const float4 b4 = *(const float4*)&Bs[k][tx * 4];
      const float a[4] = {a4.x, a4.y, a4.z, a4.w};
      const float b[4] = {b4.x, b4.y, b4.z, b4.w};
#pragma unroll
      for (int i = 0; i < 4; ++i)
#pragma unroll
        for (int j = 0; j < 4; ++j)
          acc[i][j] = fmaf(a[i], b[j], acc[i][j]);
    }
    __syncthreads();
  }

  const float4 bb = *(const float4*)&bias[col0 + tx * 4];
#pragma unroll
  for (int i = 0; i < 4; ++i) {
    float4 o;
    o.x = acc[i][0] + bb.x;
    o.y = acc[i][1] + bb.y;
    o.z = acc[i][2] + bb.z;
    o.w = acc[i][3] + bb.w;
    *(float4*)&C[(size_t)(row0 + ty * 4 + i) * N + col0 + tx * 4] = o;
  }
}

// ---------------------------------------------------------------------------
// Sliding-window attention, LDS-tiled.
// qkv layout: [B, L, 3, H, HD]. out layout: [B, L, D] (heads concatenated).
// One 256-thread block per (b, h, 32-query tile). Band |i-j| <= 128.
// Phase 1: S = Q @ K^T per 32-key chunk (K staged transposed in LDS).
// Phase 2: softmax over the 288-wide LDS score slab (stored transposed [j][q]).
// Phase 3: O = P @ V per 32-key chunk (V staged natural in LDS).
// ---------------------------------------------------------------------------
__global__ __launch_bounds__(256) void win_attn(const float* __restrict__ qkv,
                                                float* __restrict__ out) {
  const int b   = blockIdx.z;
  const int h   = blockIdx.y;
  const int i0  = blockIdx.x * TQ;
  const int tid = threadIdx.x;
  const int jlo = i0 - HALF_;  // window start (may be negative)

  // one buffer, manual layout: 2048 (Qt) + 4352 (KV) + 288*34 (St) = 16192 f
  __shared__ float smem[2048 + HD_ * KVS + WTOT * STS];
  float* Qt = smem;                    // [d][q], stride TQ (dead after phase 1)
  float* KV = smem + 2048;             // Kt: [d][j] / V: [j][d], stride KVS
  float* St = smem + 2048 + HD_ * KVS; // [jrel][q], stride STS
  float* red    = smem;        // alias Qt region (dead): [8][32]
  float* rowmax = smem + 256;  // [32]
  float* rinv   = smem + 288;  // [32]

  // ---- load Q tile transposed: Qt[d][q]
  {
    const int q = tid >> 3, d0 = (tid & 7) * 8;
    const float* src =
        &qkv[(((size_t)(b * L_ + i0 + q) * 3 + 0) * D_) + h * HD_ + d0];
    const float4 a = *(const float4*)&src[0];
    const float4 c = *(const float4*)&src[4];
    Qt[(d0 + 0) * TQ + q] = a.x; Qt[(d0 + 1) * TQ + q] = a.y;
    Qt[(d0 + 2) * TQ + q] = a.z; Qt[(d0 + 3) * TQ + q] = a.w;
    Qt[(d0 + 4) * TQ + q] = c.x; Qt[(d0 + 5) * TQ + q] = c.y;
    Qt[(d0 + 6) * TQ + q] = c.z; Qt[(d0 + 7) * TQ + q] = c.w;
  }

  const float scale = 0.125f;  // 1/sqrt(64)
  const int sq0 = (tid >> 4) * 2;  // 0..30
  const int sj0 = (tid & 15) * 2;  // 0..30

  // ---- phase 1: scores, chunked over keys
  for (int c = 0; c < NCH; ++c) {
    const int jbase = jlo + c * CH;
    {  // stage K chunk transposed: KV[d][jc]
      const int jc = tid >> 3, d0 = (tid & 7) * 4;  // d0 and d0+32
      const int j   = jbase + jc;
      const int jcl = min(max(j, 0), L_ - 1);
      const float* kp =
          &qkv[(((size_t)(b * L_ + jcl) * 3 + 1) * D_) + h * HD_];
      const float4 k0 = *(const float4*)&kp[d0];
      const float4 k1 = *(const float4*)&kp[d0 + 32];
      KV[(d0 + 0) * KVS + jc] = k0.x; KV[(d0 + 1) * KVS + jc] = k0.y;
      KV[(d0 + 2) * KVS + jc] = k0.z; KV[(d0 + 3) * KVS + jc] = k0.w;
      KV[(d0 + 32) * KVS + jc] = k1.x; KV[(d0 + 33) * KVS + jc] = k1.y;
      KV[(d0 + 34) * KVS + jc] = k1.z; KV[(d0 + 35) * KVS + jc] = k1.w;
    }
    __syncthreads();

    float acc[2][2] = {};
#pragma unroll 16
    for (int d = 0; d < HD_; ++d) {
      const float2 qv = *(const float2*)&Qt[d * TQ + sq0];
      const float2 kv = *(const float2*)&KV[d * KVS + sj0];
      acc[0][0] = fmaf(qv.x, kv.x, acc[0][0]);
      acc[0][1] = fmaf(qv.x, kv.y, acc[0][1]);
      acc[1][0] = fmaf(qv.y, kv.x, acc[1][0]);
      acc[1][1] = fmaf(qv.y, kv.y, acc[1][1]);
    }
#pragma unroll
    for (int jj = 0; jj < 2; ++jj) {
      const int j = jbase + sj0 + jj;
      const int i = i0 + sq0;
      float2 o;
      o.x = (j >= 0 && j < L_ && abs(i + 0 - j) <= HALF_)
                ? acc[0][jj] * scale : -INFINITY;
      o.y = (j >= 0 && j < L_ && abs(i + 1 - j) <= HALF_)
                ? acc[1][jj] * scale : -INFINITY;
      *(float2*)&St[(c * CH + sj0 + jj) * STS + sq0] = o;
    }
    __syncthreads();
  }

  // ---- phase 2: softmax over St columns (per query q)
  {
    const int q = tid & 31, jp = tid >> 5;
    float m = -INFINITY;
    for (int jc = jp; jc < WTOT; jc += 8) m = fmaxf(m, St[jc * STS + q]);
    red[jp * 32 + q] = m;
    __syncthreads();
    if (jp == 0) {
      float mm = red[q];
#pragma unroll
      for (int u = 1; u < 8; ++u) mm = fmaxf(mm, red[u * 32 + q]);
      rowmax[q] = mm;
    }
    __syncthreads();
    const float mrow = rowmax[q];
    float ssum = 0.f;
    for (int jc = jp; jc < WTOT; jc += 8) {
      const float e = __expf(St[jc * STS + q] - mrow);  // exp(-inf)=0 masks
      St[jc * STS + q] = e;
      ssum += e;
    }
    __syncthreads();  // all St updates visible before reduce reads red slots
    red[jp * 32 + q] = ssum;
    __syncthreads();
    if (jp == 0) {
      float ss = 0.f;
#pragma unroll
      for (int u = 0; u < 8; ++u) ss += red[u * 32 + q];
      rinv[q] = 1.f / ss;
    }
    __syncthreads();
  }

  // ---- phase 3: O = P @ V, chunked over keys
  const int pd0 = (tid & 15) * 4;  // 0..60
  const int pq0 = (tid >> 4) * 2;  // 0..30
  float po[2][4] = {};
  for (int c = 0; c < NCH; ++c) {
    const int jbase = jlo + c * CH;
    {  // stage V chunk natural: KV[jc][d]
      const int jc = tid >> 3, d0 = (tid & 7) * 8;
      const int j   = jbase + jc;
      const int jcl = min(max(j, 0), L_ - 1);
      const float* vp =
          &qkv[(((size_t)(b * L_ + jcl) * 3 + 2) * D_) + h * HD_ + d0];
      const float4 v0 = *(const float4*)&vp[0];
      const float4 v1 = *(const float4*)&vp[4];
      *(float4*)&KV[jc * KVS + d0] = v0;
      *(float4*)&KV[jc * KVS + d0 + 4] = v1;
    }
    __syncthreads();

#pragma unroll 8
    for (int jc = 0; jc < CH; ++jc) {
      const float2 p = *(const float2*)&St[(c * CH + jc) * STS + pq0];
      const float4 v = *(const float4*)&KV[jc * KVS + pd0];
      po[0][0] = fmaf(p.x, v.x, po[0][0]);
      po[0][1] = fmaf(p.x, v.y, po[0][1]);
      po[0][2] = fmaf(p.x, v.z, po[0][2]);
      po[0][3] = fmaf(p.x, v.w, po[0][3]);
      po[1][0] = fmaf(p.y, v.x, po[1][0]);
      po[1][1] = fmaf(p.y, v.y, po[1][1]);
      po[1][2] = fmaf(p.y, v.z, po[1][2]);
      po[1][3] = fmaf(p.y, v.w, po[1][3]);
    }
    __syncthreads();
  }

#pragma unroll
  for (int qq = 0; qq < 2; ++qq) {
    const float r = rinv[pq0 + qq];
    float4 o;
    o.x = po[qq][0] * r; o.y = po[qq][1] * r;
    o.z = po[qq][2] * r; o.w = po[qq][3] * r;
    *(float4*)&out[((size_t)(b * L_ + i0 + pq0 + qq)) * D_ + h * HD_ + pd0] = o;
  }
}

// ---------------------------------------------------------------------------
extern "C" void kernel_launch(void* const* d_in, const int* in_sizes, int n_in,
                              void* d_out, int out_size, void* d_ws, size_t ws_size,
                              hipStream_t stream) {
  const float* x     = (const float*)d_in[0];
  const float* w_qkv = (const float*)d_in[1];
  const float* b_qkv = (const float*)d_in[2];
  const float* w_out = (const float*)d_in[3];
  const float* b_out = (const float*)d_in[4];
  float* out = (float*)d_out;

  float* qkv  = (float*)d_ws;                       // [B,L,3,H,HD] 50.3 MB
  float* attn = qkv + (size_t)B_ * L_ * 3 * D_;     // [B,L,D]      16.8 MB

  const int M = B_ * L_;  // 4096

  {  // QKV projection: [4096,1024] @ [1024,3072] + b_qkv
    dim3 grid(3 * D_ / 64, M / 64), block(16, 16);
    sgemm_bias<64, 64, 16><<<grid, block, 0, stream>>>(x, w_qkv, b_qkv, qkv,
                                                       M, 3 * D_, D_);
  }
  {  // banded attention
    dim3 grid(L_ / TQ, H_, B_), block(256);
    win_attn<<<grid, block, 0, stream>>>(qkv, attn);
  }
  {  // output projection: [4096,1024] @ [1024,1024] + b_out
    dim3 grid(D_ / 64, M / 64), block(16, 16);
    sgemm_bias<64, 64, 16><<<grid, block, 0, stream>>>(attn, w_out, b_out, out,
                                                       M, D_, D_);
  }
}

// Round 3
// 380.220 us; speedup vs baseline: 3.1662x; 1.8505x over previous
//
#include <hip/hip_runtime.h>
#include <math.h>

#define B_    2
#define L_    2048
#define D_    1024
#define H_    16
#define HD_   64
#define HALF_ 128
#define TQ    32
#define CH    32
#define NCH   9
#define WTOT  (CH * NCH)
#define KVS   (HD_ + 4)
#define STS   (TQ + 2)

typedef __attribute__((ext_vector_type(8))) short short8;
typedef __attribute__((ext_vector_type(4))) float f32x4;

// ---- bf16 helpers (bitwise, RNE) -----------------------------------------
__device__ __forceinline__ unsigned short f2bf(float x) {
  unsigned int u = __float_as_uint(x);
  u = (u + 0x7fffu + ((u >> 16) & 1u)) >> 16;
  return (unsigned short)u;
}
__device__ __forceinline__ float bf2f(unsigned short b) {
  return __uint_as_float(((unsigned int)b) << 16);
}
__device__ __forceinline__ void split1(float a, unsigned short& h, unsigned short& l) {
  h = f2bf(a);
  l = f2bf(a - bf2f(h));
}

__device__ __forceinline__ void async_cp16(const unsigned short* g, unsigned short* l) {
  __builtin_amdgcn_global_load_lds(
      (const __attribute__((address_space(1))) unsigned int*)g,
      (__attribute__((address_space(3))) unsigned int*)l, 16, 0, 0);
}

// ---------------------------------------------------------------------------
// split_rm: fp32[n] -> hi/lo bf16[n] (row-major, 4 elems/thread)
// ---------------------------------------------------------------------------
__global__ __launch_bounds__(256) void split_rm(const float* __restrict__ in,
                                                unsigned short* __restrict__ hi,
                                                unsigned short* __restrict__ lo) {
  const int i = (blockIdx.x * 256 + threadIdx.x) * 4;
  const float4 a = *(const float4*)&in[i];
  ushort4 h, l;
  split1(a.x, h.x, l.x);
  split1(a.y, h.y, l.y);
  split1(a.z, h.z, l.z);
  split1(a.w, h.w, l.w);
  *(ushort4*)&hi[i] = h;
  *(ushort4*)&lo[i] = l;
}

// ---------------------------------------------------------------------------
// transpose_split: fp32 in[K][N] -> bf16 hi/lo out[N][K]
// 32x32 tiles; blockIdx.x = n-tile, blockIdx.y = k-tile
// ---------------------------------------------------------------------------
__global__ __launch_bounds__(256) void transpose_split(const float* __restrict__ in,
                                                       unsigned short* __restrict__ hi,
                                                       unsigned short* __restrict__ lo,
                                                       int N, int K) {
  __shared__ float t[32][33];
  const int tid = threadIdx.x;
  const int n0 = blockIdx.x * 32, k0 = blockIdx.y * 32;
  {
    const int kl = tid >> 3, nl = (tid & 7) * 4;
    const float4 v = *(const float4*)&in[(size_t)(k0 + kl) * N + n0 + nl];
    t[kl][nl + 0] = v.x; t[kl][nl + 1] = v.y;
    t[kl][nl + 2] = v.z; t[kl][nl + 3] = v.w;
  }
  __syncthreads();
  {
    const int no = tid >> 3, ko = (tid & 7) * 4;
    ushort4 h, l;
    split1(t[ko + 0][no], h.x, l.x);
    split1(t[ko + 1][no], h.y, l.y);
    split1(t[ko + 2][no], h.z, l.z);
    split1(t[ko + 3][no], h.w, l.w);
    const size_t o = (size_t)(n0 + no) * K + k0 + ko;
    *(ushort4*)&hi[o] = h;
    *(ushort4*)&lo[o] = l;
  }
}

// ---------------------------------------------------------------------------
// Split-bf16 MFMA GEMM: C[M,N] = A[M,K] @ Bt[N,K]^T + bias
// A,Bt given as (hi,lo) bf16 pairs. 128x128 tile, BK=32, 256 thr (4 waves),
// each wave a 64x64 quadrant as 4x4 grid of 16x16x32 MFMAs, 3 products each.
// LDS: 4 x 8KB buffers (Ah,Al,Bh,Bl), 64B rows, chunk-XOR swizzled.
// ---------------------------------------------------------------------------
__global__ __launch_bounds__(256) void gemm_split(const unsigned short* __restrict__ Ah,
                                                  const unsigned short* __restrict__ Al,
                                                  const unsigned short* __restrict__ Bh,
                                                  const unsigned short* __restrict__ Bl,
                                                  const float* __restrict__ bias,
                                                  float* __restrict__ C,
                                                  int N, int K) {
  __shared__ unsigned short sm[4 * 4096];  // 32 KB
  const int tid  = threadIdx.x;
  const int wave = tid >> 6, lane = tid & 63;
  const int m0 = blockIdx.y * 128, n0 = blockIdx.x * 128;
  const int wm = (wave >> 1) * 64, wn = (wave & 1) * 64;

  // staging: wave -> one buffer
  const unsigned short* src = (wave == 0) ? Ah : (wave == 1) ? Al
                              : (wave == 2) ? Bh : Bl;
  const int baserow = (wave < 2) ? m0 : n0;
  size_t goff[8];
#pragma unroll
  for (int inst = 0; inst < 8; ++inst) {
    const int r = inst * 16 + (lane >> 2);
    const int q = (lane & 3) ^ ((r >> 1) & 3);
    goff[inst] = (size_t)(baserow + r) * K + q * 8;
  }
  unsigned short* dst0 = &sm[wave * 4096];  // wave*8192 bytes

  // fragment LDS byte offsets (constant across K loop)
  int offA[4], offB[4];
#pragma unroll
  for (int t = 0; t < 4; ++t) {
    const int r = wm + t * 16 + (lane & 15);
    offA[t] = r * 64 + (((lane >> 4) ^ ((r >> 1) & 3)) * 16);
    const int rn = wn + t * 16 + (lane & 15);
    offB[t] = rn * 64 + (((lane >> 4) ^ ((rn >> 1) & 3)) * 16);
  }

  f32x4 acc[4][4] = {};
  const char* smb = (const char*)sm;

  for (int k0 = 0; k0 < K; k0 += 32) {
#pragma unroll
    for (int inst = 0; inst < 8; ++inst)
      async_cp16(src + goff[inst] + k0,
                 (unsigned short*)((char*)dst0 + inst * 1024));
    __syncthreads();

    short8 ah[4], al[4], bh[4], bl[4];
#pragma unroll
    for (int t = 0; t < 4; ++t) {
      ah[t] = *(const short8*)(smb + offA[t]);
      al[t] = *(const short8*)(smb + 8192 + offA[t]);
      bh[t] = *(const short8*)(smb + 16384 + offB[t]);
      bl[t] = *(const short8*)(smb + 24576 + offB[t]);
    }
#pragma unroll
    for (int t = 0; t < 4; ++t)
#pragma unroll
      for (int u = 0; u < 4; ++u) {
        acc[t][u] = __builtin_amdgcn_mfma_f32_16x16x32_bf16(ah[t], bh[u], acc[t][u], 0, 0, 0);
        acc[t][u] = __builtin_amdgcn_mfma_f32_16x16x32_bf16(ah[t], bl[u], acc[t][u], 0, 0, 0);
        acc[t][u] = __builtin_amdgcn_mfma_f32_16x16x32_bf16(al[t], bh[u], acc[t][u], 0, 0, 0);
      }
    __syncthreads();
  }

#pragma unroll
  for (int u = 0; u < 4; ++u) {
    const int col = n0 + wn + u * 16 + (lane & 15);
    const float bv = bias[col];
#pragma unroll
    for (int t = 0; t < 4; ++t) {
      const int row0 = m0 + wm + t * 16 + ((lane >> 4) << 2);
#pragma unroll
      for (int e = 0; e < 4; ++e)
        C[(size_t)(row0 + e) * N + col] = acc[t][u][e] + bv;
    }
  }
}

// ---------------------------------------------------------------------------
// Sliding-window attention (unchanged from round 2)
// ---------------------------------------------------------------------------
__global__ __launch_bounds__(256) void win_attn(const float* __restrict__ qkv,
                                                float* __restrict__ out) {
  const int b   = blockIdx.z;
  const int h   = blockIdx.y;
  const int i0  = blockIdx.x * TQ;
  const int tid = threadIdx.x;
  const int jlo = i0 - HALF_;

  __shared__ float smem[2048 + HD_ * KVS + WTOT * STS];
  float* Qt = smem;
  float* KV = smem + 2048;
  float* St = smem + 2048 + HD_ * KVS;
  float* red    = smem;
  float* rowmax = smem + 256;
  float* rinv   = smem + 288;

  {
    const int q = tid >> 3, d0 = (tid & 7) * 8;
    const float* src =
        &qkv[(((size_t)(b * L_ + i0 + q) * 3 + 0) * D_) + h * HD_ + d0];
    const float4 a = *(const float4*)&src[0];
    const float4 c = *(const float4*)&src[4];
    Qt[(d0 + 0) * TQ + q] = a.x; Qt[(d0 + 1) * TQ + q] = a.y;
    Qt[(d0 + 2) * TQ + q] = a.z; Qt[(d0 + 3) * TQ + q] = a.w;
    Qt[(d0 + 4) * TQ + q] = c.x; Qt[(d0 + 5) * TQ + q] = c.y;
    Qt[(d0 + 6) * TQ + q] = c.z; Qt[(d0 + 7) * TQ + q] = c.w;
  }

  const float scale = 0.125f;
  const int sq0 = (tid >> 4) * 2;
  const int sj0 = (tid & 15) * 2;

  for (int c = 0; c < NCH; ++c) {
    const int jbase = jlo + c * CH;
    {
      const int jc = tid >> 3, d0 = (tid & 7) * 4;
      const int j   = jbase + jc;
      const int jcl = min(max(j, 0), L_ - 1);
      const float* kp =
          &qkv[(((size_t)(b * L_ + jcl) * 3 + 1) * D_) + h * HD_];
      const float4 k0 = *(const float4*)&kp[d0];
      const float4 k1 = *(const float4*)&kp[d0 + 32];
      KV[(d0 + 0) * KVS + jc] = k0.x; KV[(d0 + 1) * KVS + jc] = k0.y;
      KV[(d0 + 2) * KVS + jc] = k0.z; KV[(d0 + 3) * KVS + jc] = k0.w;
      KV[(d0 + 32) * KVS + jc] = k1.x; KV[(d0 + 33) * KVS + jc] = k1.y;
      KV[(d0 + 34) * KVS + jc] = k1.z; KV[(d0 + 35) * KVS + jc] = k1.w;
    }
    __syncthreads();

    float acc[2][2] = {};
#pragma unroll 16
    for (int d = 0; d < HD_; ++d) {
      const float2 qv = *(const float2*)&Qt[d * TQ + sq0];
      const float2 kv = *(const float2*)&KV[d * KVS + sj0];
      acc[0][0] = fmaf(qv.x, kv.x, acc[0][0]);
      acc[0][1] = fmaf(qv.x, kv.y, acc[0][1]);
      acc[1][0] = fmaf(qv.y, kv.x, acc[1][0]);
      acc[1][1] = fmaf(qv.y, kv.y, acc[1][1]);
    }
#pragma unroll
    for (int jj = 0; jj < 2; ++jj) {
      const int j = jbase + sj0 + jj;
      const int i = i0 + sq0;
      float2 o;
      o.x = (j >= 0 && j < L_ && abs(i + 0 - j) <= HALF_)
                ? acc[0][jj] * scale : -INFINITY;
      o.y = (j >= 0 && j < L_ && abs(i + 1 - j) <= HALF_)
                ? acc[1][jj] * scale : -INFINITY;
      *(float2*)&St[(c * CH + sj0 + jj) * STS + sq0] = o;
    }
    __syncthreads();
  }

  {
    const int q = tid & 31, jp = tid >> 5;
    float m = -INFINITY;
    for (int jc = jp; jc < WTOT; jc += 8) m = fmaxf(m, St[jc * STS + q]);
    red[jp * 32 + q] = m;
    __syncthreads();
    if (jp == 0) {
      float mm = red[q];
#pragma unroll
      for (int u = 1; u < 8; ++u) mm = fmaxf(mm, red[u * 32 + q]);
      rowmax[q] = mm;
    }
    __syncthreads();
    const float mrow = rowmax[q];
    float ssum = 0.f;
    for (int jc = jp; jc < WTOT; jc += 8) {
      const float e = __expf(St[jc * STS + q] - mrow);
      St[jc * STS + q] = e;
      ssum += e;
    }
    __syncthreads();
    red[jp * 32 + q] = ssum;
    __syncthreads();
    if (jp == 0) {
      float ss = 0.f;
#pragma unroll
      for (int u = 0; u < 8; ++u) ss += red[u * 32 + q];
      rinv[q] = 1.f / ss;
    }
    __syncthreads();
  }

  const int pd0 = (tid & 15) * 4;
  const int pq0 = (tid >> 4) * 2;
  float po[2][4] = {};
  for (int c = 0; c < NCH; ++c) {
    const int jbase = jlo + c * CH;
    {
      const int jc = tid >> 3, d0 = (tid & 7) * 8;
      const int j   = jbase + jc;
      const int jcl = min(max(j, 0), L_ - 1);
      const float* vp =
          &qkv[(((size_t)(b * L_ + jcl) * 3 + 2) * D_) + h * HD_ + d0];
      const float4 v0 = *(const float4*)&vp[0];
      const float4 v1 = *(const float4*)&vp[4];
      *(float4*)&KV[jc * KVS + d0] = v0;
      *(float4*)&KV[jc * KVS + d0 + 4] = v1;
    }
    __syncthreads();

#pragma unroll 8
    for (int jc = 0; jc < CH; ++jc) {
      const float2 p = *(const float2*)&St[(c * CH + jc) * STS + pq0];
      const float4 v = *(const float4*)&KV[jc * KVS + pd0];
      po[0][0] = fmaf(p.x, v.x, po[0][0]);
      po[0][1] = fmaf(p.x, v.y, po[0][1]);
      po[0][2] = fmaf(p.x, v.z, po[0][2]);
      po[0][3] = fmaf(p.x, v.w, po[0][3]);
      po[1][0] = fmaf(p.y, v.x, po[1][0]);
      po[1][1] = fmaf(p.y, v.y, po[1][1]);
      po[1][2] = fmaf(p.y, v.z, po[1][2]);
      po[1][3] = fmaf(p.y, v.w, po[1][3]);
    }
    __syncthreads();
  }

#pragma unroll
  for (int qq = 0; qq < 2; ++qq) {
    const float r = rinv[pq0 + qq];
    float4 o;
    o.x = po[qq][0] * r; o.y = po[qq][1] * r;
    o.z = po[qq][2] * r; o.w = po[qq][3] * r;
    *(float4*)&out[((size_t)(b * L_ + i0 + pq0 + qq)) * D_ + h * HD_ + pd0] = o;
  }
}

// ---------------------------------------------------------------------------
extern "C" void kernel_launch(void* const* d_in, const int* in_sizes, int n_in,
                              void* d_out, int out_size, void* d_ws, size_t ws_size,
                              hipStream_t stream) {
  const float* x     = (const float*)d_in[0];
  const float* w_qkv = (const float*)d_in[1];
  const float* b_qkv = (const float*)d_in[2];
  const float* w_out = (const float*)d_in[3];
  const float* b_out = (const float*)d_in[4];
  float* out = (float*)d_out;

  const int M = B_ * L_;  // 4096

  // workspace layout (bytes):
  // [0, 50.33MB)   qkv fp32            (dead after win_attn; tail reused)
  // [50.33, 58.72) x_hi   [58.72, 67.11) x_lo          (bf16, M*D)
  // [67.11, 73.40) wqkvT_hi  [73.40, 79.69) wqkvT_lo   (bf16, 3D*D)
  // aliases over dead qkv region:
  // [0, 8.39)  attn_hi  [8.39, 16.78) attn_lo          (bf16, M*D)
  // [16.78, 18.87) woutT_hi  [18.87, 20.97) woutT_lo   (bf16, D*D)
  char* ws = (char*)d_ws;
  float*          qkv      = (float*)ws;
  unsigned short* x_hi     = (unsigned short*)(ws + 50331648);
  unsigned short* x_lo     = (unsigned short*)(ws + 58720256);
  unsigned short* wqkvT_hi = (unsigned short*)(ws + 67108864);
  unsigned short* wqkvT_lo = (unsigned short*)(ws + 73400320);
  unsigned short* attn_hi  = (unsigned short*)(ws + 0);
  unsigned short* attn_lo  = (unsigned short*)(ws + 8388608);
  unsigned short* woutT_hi = (unsigned short*)(ws + 16777216);
  unsigned short* woutT_lo = (unsigned short*)(ws + 18874368);

  // 1) split x -> bf16 hi/lo
  split_rm<<<M * D_ / 1024, 256, 0, stream>>>(x, x_hi, x_lo);
  // 2) transpose+split w_qkv [D,3D] -> [3D,D]
  {
    dim3 g(3 * D_ / 32, D_ / 32);
    transpose_split<<<g, 256, 0, stream>>>(w_qkv, wqkvT_hi, wqkvT_lo, 3 * D_, D_);
  }
  // 3) QKV projection via split-bf16 MFMA
  {
    dim3 g(3 * D_ / 128, M / 128);
    gemm_split<<<g, 256, 0, stream>>>(x_hi, x_lo, wqkvT_hi, wqkvT_lo, b_qkv,
                                      qkv, 3 * D_, D_);
  }
  // 4) banded attention -> d_out (temporary fp32 buffer)
  {
    dim3 g(L_ / TQ, H_, B_);
    win_attn<<<g, 256, 0, stream>>>(qkv, out);
  }
  // 5) split attention output (reads d_out, writes ws)
  split_rm<<<M * D_ / 1024, 256, 0, stream>>>(out, attn_hi, attn_lo);
  // 6) transpose+split w_out [D,D] -> [D,D]
  {
    dim3 g(D_ / 32, D_ / 32);
    transpose_split<<<g, 256, 0, stream>>>(w_out, woutT_hi, woutT_lo, D_, D_);
  }
  // 7) output projection via split-bf16 MFMA -> d_out
  {
    dim3 g(D_ / 128, M / 128);
    gemm_split<<<g, 256, 0, stream>>>(attn_hi, attn_lo, woutT_hi, woutT_lo,
                                      b_out, out, D_, D_);
  }
}

// Round 4
// 302.108 us; speedup vs baseline: 3.9848x; 1.2586x over previous
//
#include <hip/hip_runtime.h>
#include <math.h>

#define B_    2
#define L_    2048
#define D_    1024
#define H_    16
#define HD_   64
#define HALF_ 128
#define TQ    32          // queries per attention block
#define WTOT  288         // window span for a 32-query tile
#define SROW  292         // fp32 score-slab row stride (floats)
#define PROW  296         // bf16 P-slab row stride (shorts)

typedef __attribute__((ext_vector_type(8))) short short8;
typedef __attribute__((ext_vector_type(4))) float f32x4;

// ---- bf16 helpers (bitwise, RNE) -----------------------------------------
__device__ __forceinline__ unsigned short f2bf(float x) {
  unsigned int u = __float_as_uint(x);
  u = (u + 0x7fffu + ((u >> 16) & 1u)) >> 16;
  return (unsigned short)u;
}
__device__ __forceinline__ float bf2f(unsigned short b) {
  return __uint_as_float(((unsigned int)b) << 16);
}
__device__ __forceinline__ void split1(float a, unsigned short& h, unsigned short& l) {
  h = f2bf(a);
  l = f2bf(a - bf2f(h));
}

__device__ __forceinline__ void async_cp16(const unsigned short* g, unsigned short* l) {
  __builtin_amdgcn_global_load_lds(
      (const __attribute__((address_space(1))) unsigned int*)g,
      (__attribute__((address_space(3))) unsigned int*)l, 16, 0, 0);
}

// ---------------------------------------------------------------------------
// split_rm: fp32[n] -> hi/lo bf16[n]
// ---------------------------------------------------------------------------
__global__ __launch_bounds__(256) void split_rm(const float* __restrict__ in,
                                                unsigned short* __restrict__ hi,
                                                unsigned short* __restrict__ lo) {
  const int i = (blockIdx.x * 256 + threadIdx.x) * 4;
  const float4 a = *(const float4*)&in[i];
  ushort4 h, l;
  split1(a.x, h.x, l.x);
  split1(a.y, h.y, l.y);
  split1(a.z, h.z, l.z);
  split1(a.w, h.w, l.w);
  *(ushort4*)&hi[i] = h;
  *(ushort4*)&lo[i] = l;
}

// ---------------------------------------------------------------------------
// transpose_split: fp32 in[K][N] -> bf16 hi/lo out[N][K]
// ---------------------------------------------------------------------------
__global__ __launch_bounds__(256) void transpose_split(const float* __restrict__ in,
                                                       unsigned short* __restrict__ hi,
                                                       unsigned short* __restrict__ lo,
                                                       int N, int K) {
  __shared__ float t[32][33];
  const int tid = threadIdx.x;
  const int n0 = blockIdx.x * 32, k0 = blockIdx.y * 32;
  {
    const int kl = tid >> 3, nl = (tid & 7) * 4;
    const float4 v = *(const float4*)&in[(size_t)(k0 + kl) * N + n0 + nl];
    t[kl][nl + 0] = v.x; t[kl][nl + 1] = v.y;
    t[kl][nl + 2] = v.z; t[kl][nl + 3] = v.w;
  }
  __syncthreads();
  {
    const int no = tid >> 3, ko = (tid & 7) * 4;
    ushort4 h, l;
    split1(t[ko + 0][no], h.x, l.x);
    split1(t[ko + 1][no], h.y, l.y);
    split1(t[ko + 2][no], h.z, l.z);
    split1(t[ko + 3][no], h.w, l.w);
    const size_t o = (size_t)(n0 + no) * K + k0 + ko;
    *(ushort4*)&hi[o] = h;
    *(ushort4*)&lo[o] = l;
  }
}

// ---------------------------------------------------------------------------
// Split-bf16 MFMA GEMM: C = A @ Bt^T + bias.  128x128 tile, BK=32, 4 waves.
// MODE 0: write fp32 C[M,N].
// MODE 1: QKV epilogue — q,k slices -> qk_h/qk_l [B,L,2,H*HD] split bf16;
//         v slice -> vT_h/vT_l [B, H*HD, L] (transposed) split bf16.
// ---------------------------------------------------------------------------
template <int MODE>
__global__ __launch_bounds__(256) void gemm_split(const unsigned short* __restrict__ Ah,
                                                  const unsigned short* __restrict__ Al,
                                                  const unsigned short* __restrict__ Bh,
                                                  const unsigned short* __restrict__ Bl,
                                                  const float* __restrict__ bias,
                                                  float* __restrict__ C,
                                                  unsigned short* __restrict__ qk_h,
                                                  unsigned short* __restrict__ qk_l,
                                                  unsigned short* __restrict__ vT_h,
                                                  unsigned short* __restrict__ vT_l,
                                                  int N, int K) {
  __shared__ unsigned short sm[4 * 4096];  // 32 KB
  const int tid  = threadIdx.x;
  const int wave = tid >> 6, lane = tid & 63;
  const int m0 = blockIdx.y * 128, n0 = blockIdx.x * 128;
  const int wm = (wave >> 1) * 64, wn = (wave & 1) * 64;

  const unsigned short* src = (wave == 0) ? Ah : (wave == 1) ? Al
                              : (wave == 2) ? Bh : Bl;
  const int baserow = (wave < 2) ? m0 : n0;
  size_t goff[8];
#pragma unroll
  for (int inst = 0; inst < 8; ++inst) {
    const int r = inst * 16 + (lane >> 2);
    const int q = (lane & 3) ^ ((r >> 1) & 3);
    goff[inst] = (size_t)(baserow + r) * K + q * 8;
  }
  unsigned short* dst0 = &sm[wave * 4096];

  int offA[4], offB[4];
#pragma unroll
  for (int t = 0; t < 4; ++t) {
    const int r = wm + t * 16 + (lane & 15);
    offA[t] = r * 64 + (((lane >> 4) ^ ((r >> 1) & 3)) * 16);
    const int rn = wn + t * 16 + (lane & 15);
    offB[t] = rn * 64 + (((lane >> 4) ^ ((rn >> 1) & 3)) * 16);
  }

  f32x4 acc[4][4] = {};
  const char* smb = (const char*)sm;

  for (int k0 = 0; k0 < K; k0 += 32) {
#pragma unroll
    for (int inst = 0; inst < 8; ++inst)
      async_cp16(src + goff[inst] + k0,
                 (unsigned short*)((char*)dst0 + inst * 1024));
    __syncthreads();

    short8 ah[4], al[4], bh[4], bl[4];
#pragma unroll
    for (int t = 0; t < 4; ++t) {
      ah[t] = *(const short8*)(smb + offA[t]);
      al[t] = *(const short8*)(smb + 8192 + offA[t]);
      bh[t] = *(const short8*)(smb + 16384 + offB[t]);
      bl[t] = *(const short8*)(smb + 24576 + offB[t]);
    }
#pragma unroll
    for (int t = 0; t < 4; ++t)
#pragma unroll
      for (int u = 0; u < 4; ++u) {
        acc[t][u] = __builtin_amdgcn_mfma_f32_16x16x32_bf16(ah[t], bh[u], acc[t][u], 0, 0, 0);
        acc[t][u] = __builtin_amdgcn_mfma_f32_16x16x32_bf16(ah[t], bl[u], acc[t][u], 0, 0, 0);
        acc[t][u] = __builtin_amdgcn_mfma_f32_16x16x32_bf16(al[t], bh[u], acc[t][u], 0, 0, 0);
      }
    __syncthreads();
  }

#pragma unroll
  for (int u = 0; u < 4; ++u) {
    const int col = n0 + wn + u * 16 + (lane & 15);
    const float bv = bias[col];
#pragma unroll
    for (int t = 0; t < 4; ++t) {
      const int row0 = m0 + wm + t * 16 + ((lane >> 4) << 2);
      if (MODE == 0) {
#pragma unroll
        for (int e = 0; e < 4; ++e)
          C[(size_t)(row0 + e) * N + col] = acc[t][u][e] + bv;
      } else {
        const int slot = col >> 10;   // 0=q,1=k,2=v (wave-uniform per tile)
        const int hd   = col & 1023;
        if (slot < 2) {
#pragma unroll
          for (int e = 0; e < 4; ++e) {
            unsigned short hh, ll;
            split1(acc[t][u][e] + bv, hh, ll);
            const size_t o = ((size_t)(row0 + e) * 2 + slot) * 1024 + hd;
            qk_h[o] = hh;
            qk_l[o] = ll;
          }
        } else {
          const int bb = row0 >> 11, l0 = row0 & 2047;
          ushort4 vh, vl;
          split1(acc[t][u][0] + bv, vh.x, vl.x);
          split1(acc[t][u][1] + bv, vh.y, vl.y);
          split1(acc[t][u][2] + bv, vh.z, vl.z);
          split1(acc[t][u][3] + bv, vh.w, vl.w);
          const size_t o = ((size_t)bb * 1024 + hd) * 2048 + l0;
          *(ushort4*)&vT_h[o] = vh;
          *(ushort4*)&vT_l[o] = vl;
        }
      }
    }
  }
}

// ---------------------------------------------------------------------------
// MFMA sliding-window attention. Block = (b, h, 32 queries), 4 waves.
// Phase 1: S = (Qh+Ql)(Kh+Kl)^T (3 products), direct global frag loads,
//          C-layout scatter to fp32 LDS slab. No barriers inside loop.
// Phase 2: softmax (reg-cached), write normalized P bf16 over the slab.
// Phase 3: O = P @ (Vh+Vl), P frags from LDS, V frags direct from vT global.
// Epilogue: split-bf16 write of O for the out-projection GEMM.
// ---------------------------------------------------------------------------
__global__ __launch_bounds__(256, 4) void attn_mfma(
    const unsigned short* __restrict__ qk_h,
    const unsigned short* __restrict__ qk_l,
    const unsigned short* __restrict__ vT_h,
    const unsigned short* __restrict__ vT_l,
    unsigned short* __restrict__ attn_h,
    unsigned short* __restrict__ attn_l) {
  __shared__ float Sf[TQ * SROW];   // 37376 B, P bf16 slab aliases this
  __shared__ float red[256];
  unsigned short* P = (unsigned short*)Sf;

  const int b   = blockIdx.z;
  const int h   = blockIdx.y;
  const int i0  = blockIdx.x * TQ;
  const int tid = threadIdx.x;
  const int wave = tid >> 6, lane = tid & 63;
  const int quad = lane >> 4, ln16 = lane & 15;
  const int jlo = i0 - HALF_;
  const int mt = wave >> 1;         // m-tile (0,1)

  // ---- phase 1: scores ----------------------------------------------------
  {
    short8 qh[2], ql[2];
    const size_t qbase =
        ((size_t)(b * L_ + i0 + mt * 16 + ln16) * 2 + 0) * 1024 + h * 64 + quad * 8;
    qh[0] = *(const short8*)&qk_h[qbase];
    qh[1] = *(const short8*)&qk_h[qbase + 32];
    ql[0] = *(const short8*)&qk_l[qbase];
    ql[1] = *(const short8*)&qk_l[qbase + 32];

    for (int c = 0; c < 9; ++c) {
      const int nt   = (wave & 1) + 2 * c;        // n-tile 0..17
      const int jabs = jlo + nt * 16 + ln16;
      const int jcl  = min(max(jabs, 0), L_ - 1);
      const size_t kbase =
          ((size_t)(b * L_ + jcl) * 2 + 1) * 1024 + h * 64 + quad * 8;
      const short8 kh0 = *(const short8*)&qk_h[kbase];
      const short8 kh1 = *(const short8*)&qk_h[kbase + 32];
      const short8 kl0 = *(const short8*)&qk_l[kbase];
      const short8 kl1 = *(const short8*)&qk_l[kbase + 32];

      f32x4 acc = {};
      acc = __builtin_amdgcn_mfma_f32_16x16x32_bf16(qh[0], kh0, acc, 0, 0, 0);
      acc = __builtin_amdgcn_mfma_f32_16x16x32_bf16(qh[0], kl0, acc, 0, 0, 0);
      acc = __builtin_amdgcn_mfma_f32_16x16x32_bf16(ql[0], kh0, acc, 0, 0, 0);
      acc = __builtin_amdgcn_mfma_f32_16x16x32_bf16(qh[1], kh1, acc, 0, 0, 0);
      acc = __builtin_amdgcn_mfma_f32_16x16x32_bf16(qh[1], kl1, acc, 0, 0, 0);
      acc = __builtin_amdgcn_mfma_f32_16x16x32_bf16(ql[1], kh1, acc, 0, 0, 0);

      const int colj  = nt * 16 + ln16;
      const int rbase = mt * 16 + quad * 4;
#pragma unroll
      for (int e = 0; e < 4; ++e) {
        const int iabs = i0 + rbase + e;
        const bool ok = (jabs >= 0) && (jabs < L_) && (abs(iabs - jabs) <= HALF_);
        Sf[(rbase + e) * SROW + colj] = ok ? acc[e] * 0.125f : -INFINITY;
      }
    }
  }
  __syncthreads();

  // ---- phase 2: softmax ---------------------------------------------------
  {
    const int q = tid >> 3, lr = tid & 7;
    float v[36];
    const float* srow = &Sf[q * SROW + lr * 36];
    float lmax = -INFINITY;
#pragma unroll
    for (int u = 0; u < 9; ++u) {
      const float4 t4 = *(const float4*)&srow[u * 4];
      v[u * 4 + 0] = t4.x; v[u * 4 + 1] = t4.y;
      v[u * 4 + 2] = t4.z; v[u * 4 + 3] = t4.w;
      lmax = fmaxf(lmax, fmaxf(fmaxf(t4.x, t4.y), fmaxf(t4.z, t4.w)));
    }
    red[tid] = lmax;
    __syncthreads();
    float mrow = red[q * 8];
#pragma unroll
    for (int u = 1; u < 8; ++u) mrow = fmaxf(mrow, red[q * 8 + u]);
    float lsum = 0.f;
#pragma unroll
    for (int i = 0; i < 36; ++i) {
      v[i] = __expf(v[i] - mrow);
      lsum += v[i];
    }
    __syncthreads();
    red[tid] = lsum;
    __syncthreads();
    float tot = 0.f;
#pragma unroll
    for (int u = 0; u < 8; ++u) tot += red[q * 8 + u];
    const float rinv = 1.f / tot;
    unsigned short* prow = &P[q * PROW + lr * 36];
#pragma unroll
    for (int i = 0; i < 36; ++i) prow[i] = f2bf(v[i] * rinv);
  }
  __syncthreads();

  // ---- phase 3: O = P @ V -------------------------------------------------
  {
    const int dp = wave & 1;
    const char* pb = (const char*)P;
    f32x4 o[2] = {};
    for (int c = 0; c < 9; ++c) {
      const short8 pf =
          *(const short8*)(pb + (mt * 16 + ln16) * (PROW * 2) + c * 64 + quad * 16);
      int j0 = jlo + c * 32 + quad * 8;
      j0 = min(max(j0, 0), L_ - 8);
#pragma unroll
      for (int t = 0; t < 2; ++t) {
        const size_t vb =
            ((size_t)b * 1024 + h * 64 + dp * 32 + t * 16 + ln16) * 2048 + j0;
        o[t] = __builtin_amdgcn_mfma_f32_16x16x32_bf16(
            pf, *(const short8*)&vT_h[vb], o[t], 0, 0, 0);
        o[t] = __builtin_amdgcn_mfma_f32_16x16x32_bf16(
            pf, *(const short8*)&vT_l[vb], o[t], 0, 0, 0);
      }
    }
#pragma unroll
    for (int t = 0; t < 2; ++t) {
      const int col = h * 64 + dp * 32 + t * 16 + ln16;
#pragma unroll
      for (int e = 0; e < 4; ++e) {
        const int row = i0 + mt * 16 + quad * 4 + e;
        unsigned short hh, ll;
        split1(o[t][e], hh, ll);
        const size_t oo = (size_t)(b * L_ + row) * 1024 + col;
        attn_h[oo] = hh;
        attn_l[oo] = ll;
      }
    }
  }
}

// ---------------------------------------------------------------------------
extern "C" void kernel_launch(void* const* d_in, const int* in_sizes, int n_in,
                              void* d_out, int out_size, void* d_ws, size_t ws_size,
                              hipStream_t stream) {
  const float* x     = (const float*)d_in[0];
  const float* w_qkv = (const float*)d_in[1];
  const float* b_qkv = (const float*)d_in[2];
  const float* w_out = (const float*)d_in[3];
  const float* b_out = (const float*)d_in[4];
  float* out = (float*)d_out;

  const int M = B_ * L_;  // 4096

  // workspace layout (bytes), total 79691776 (= round-3 footprint):
  //   x_hi @0 (8MiB)        x_lo @8MiB        [dead after QKV gemm]
  //   wqkvT_hi @16MiB (6MiB) wqkvT_lo @22MiB  [dead after QKV gemm]
  //   qk_hi @28MiB (16MiB)  qk_lo @44MiB      [B,L,2,1024]
  //   vT_hi @60MiB (8MiB)   vT_lo @68MiB      [B,1024,L]
  // aliases over dead regions:
  //   attn_hi @0, attn_lo @8MiB;  woutT_hi @16MiB, woutT_lo @18MiB
  char* ws = (char*)d_ws;
  unsigned short* x_hi     = (unsigned short*)(ws + 0);
  unsigned short* x_lo     = (unsigned short*)(ws + 8388608);
  unsigned short* wqkvT_hi = (unsigned short*)(ws + 16777216);
  unsigned short* wqkvT_lo = (unsigned short*)(ws + 23068672);
  unsigned short* qk_hi    = (unsigned short*)(ws + 29360128);
  unsigned short* qk_lo    = (unsigned short*)(ws + 46137344);
  unsigned short* vT_hi    = (unsigned short*)(ws + 62914560);
  unsigned short* vT_lo    = (unsigned short*)(ws + 71303168);
  unsigned short* attn_hi  = (unsigned short*)(ws + 0);
  unsigned short* attn_lo  = (unsigned short*)(ws + 8388608);
  unsigned short* woutT_hi = (unsigned short*)(ws + 16777216);
  unsigned short* woutT_lo = (unsigned short*)(ws + 18874368);

  // 1) split x -> bf16 hi/lo
  split_rm<<<M * D_ / 1024, 256, 0, stream>>>(x, x_hi, x_lo);
  // 2) transpose+split w_qkv [D,3D] -> [3D,D]
  {
    dim3 g(3 * D_ / 32, D_ / 32);
    transpose_split<<<g, 256, 0, stream>>>(w_qkv, wqkvT_hi, wqkvT_lo, 3 * D_, D_);
  }
  // 3) QKV projection -> qk (split bf16) + vT (split bf16, transposed)
  {
    dim3 g(3 * D_ / 128, M / 128);
    gemm_split<1><<<g, 256, 0, stream>>>(x_hi, x_lo, wqkvT_hi, wqkvT_lo, b_qkv,
                                         nullptr, qk_hi, qk_lo, vT_hi, vT_lo,
                                         3 * D_, D_);
  }
  // 4) transpose+split w_out [D,D] -> [D,D]  (after step 3: aliases wqkvT)
  {
    dim3 g(D_ / 32, D_ / 32);
    transpose_split<<<g, 256, 0, stream>>>(w_out, woutT_hi, woutT_lo, D_, D_);
  }
  // 5) MFMA banded attention -> attn split bf16 (aliases dead x)
  {
    dim3 g(L_ / TQ, H_, B_);
    attn_mfma<<<g, 256, 0, stream>>>(qk_hi, qk_lo, vT_hi, vT_lo, attn_hi, attn_lo);
  }
  // 6) output projection -> fp32 d_out
  {
    dim3 g(D_ / 128, M / 128);
    gemm_split<0><<<g, 256, 0, stream>>>(attn_hi, attn_lo, woutT_hi, woutT_lo,
                                         b_out, out, nullptr, nullptr, nullptr,
                                         nullptr, D_, D_);
  }
}

// Round 5
// 241.452 us; speedup vs baseline: 4.9858x; 1.2512x over previous
//
#include <hip/hip_runtime.h>
#include <math.h>

#define B_    2
#define L_    2048
#define D_    1024
#define H_    16
#define HD_   64
#define HALF_ 128
#define TQ    32          // queries per attention block
#define WTOT  288         // window span for a 32-query tile
#define SROW  292         // fp32 score-slab row stride (floats)
#define PROW  296         // bf16 P-slab row stride (shorts)

typedef __attribute__((ext_vector_type(8))) short short8;
typedef __attribute__((ext_vector_type(4))) float f32x4;

// ---- bf16 helpers (bitwise, RNE) -----------------------------------------
__device__ __forceinline__ unsigned short f2bf(float x) {
  unsigned int u = __float_as_uint(x);
  u = (u + 0x7fffu + ((u >> 16) & 1u)) >> 16;
  return (unsigned short)u;
}
__device__ __forceinline__ float bf2f(unsigned short b) {
  return __uint_as_float(((unsigned int)b) << 16);
}
__device__ __forceinline__ void split1(float a, unsigned short& h, unsigned short& l) {
  h = f2bf(a);
  l = f2bf(a - bf2f(h));
}

__device__ __forceinline__ void async_cp16(const unsigned short* g, unsigned short* l) {
  __builtin_amdgcn_global_load_lds(
      (const __attribute__((address_space(1))) unsigned int*)g,
      (__attribute__((address_space(3))) unsigned int*)l, 16, 0, 0);
}

// ---------------------------------------------------------------------------
// split_rm: fp32[n] -> hi/lo bf16[n]
// ---------------------------------------------------------------------------
__global__ __launch_bounds__(256) void split_rm(const float* __restrict__ in,
                                                unsigned short* __restrict__ hi,
                                                unsigned short* __restrict__ lo) {
  const int i = (blockIdx.x * 256 + threadIdx.x) * 4;
  const float4 a = *(const float4*)&in[i];
  ushort4 h, l;
  split1(a.x, h.x, l.x);
  split1(a.y, h.y, l.y);
  split1(a.z, h.z, l.z);
  split1(a.w, h.w, l.w);
  *(ushort4*)&hi[i] = h;
  *(ushort4*)&lo[i] = l;
}

// ---------------------------------------------------------------------------
// transpose_round: fp32 in[K][N] -> bf16 out[N][K] (RNE, hi only)
// ---------------------------------------------------------------------------
__global__ __launch_bounds__(256) void transpose_round(const float* __restrict__ in,
                                                       unsigned short* __restrict__ hi,
                                                       int N, int K) {
  __shared__ float t[32][33];
  const int tid = threadIdx.x;
  const int n0 = blockIdx.x * 32, k0 = blockIdx.y * 32;
  {
    const int kl = tid >> 3, nl = (tid & 7) * 4;
    const float4 v = *(const float4*)&in[(size_t)(k0 + kl) * N + n0 + nl];
    t[kl][nl + 0] = v.x; t[kl][nl + 1] = v.y;
    t[kl][nl + 2] = v.z; t[kl][nl + 3] = v.w;
  }
  __syncthreads();
  {
    const int no = tid >> 3, ko = (tid & 7) * 4;
    ushort4 h;
    h.x = f2bf(t[ko + 0][no]);
    h.y = f2bf(t[ko + 1][no]);
    h.z = f2bf(t[ko + 2][no]);
    h.w = f2bf(t[ko + 3][no]);
    *(ushort4*)&hi[(size_t)(n0 + no) * K + k0 + ko] = h;
  }
}

// ---------------------------------------------------------------------------
// 2-product split-bf16 MFMA GEMM: C = (Ah+Al) @ Bh^T + bias.
// 128x128 tile, BK=32, 4 waves (3 stage, all compute).
// MODE 0: write fp32 C[M,N].
// MODE 1: QKV epilogue — q,k -> qk_h/qk_l [B,L,2,1024]; v -> vT_h/vT_l [B,1024,L].
// ---------------------------------------------------------------------------
template <int MODE>
__global__ __launch_bounds__(256) void gemm_split(const unsigned short* __restrict__ Ah,
                                                  const unsigned short* __restrict__ Al,
                                                  const unsigned short* __restrict__ Bh,
                                                  const float* __restrict__ bias,
                                                  float* __restrict__ C,
                                                  unsigned short* __restrict__ qk_h,
                                                  unsigned short* __restrict__ qk_l,
                                                  unsigned short* __restrict__ vT_h,
                                                  unsigned short* __restrict__ vT_l,
                                                  int N, int K) {
  __shared__ unsigned short sm[3 * 4096];  // 24 KB: Ah | Al | Bh
  const int tid  = threadIdx.x;
  const int wave = tid >> 6, lane = tid & 63;
  const int m0 = blockIdx.y * 128, n0 = blockIdx.x * 128;
  const int wm = (wave >> 1) * 64, wn = (wave & 1) * 64;

  const unsigned short* src = (wave == 0) ? Ah : (wave == 1) ? Al : Bh;
  const int baserow = (wave < 2) ? m0 : n0;
  size_t goff[8];
#pragma unroll
  for (int inst = 0; inst < 8; ++inst) {
    const int r = inst * 16 + (lane >> 2);
    const int q = (lane & 3) ^ ((r >> 1) & 3);
    goff[inst] = (size_t)(baserow + r) * K + q * 8;
  }
  unsigned short* dst0 = &sm[(wave < 3 ? wave : 2) * 4096];

  int offA[4], offB[4];
#pragma unroll
  for (int t = 0; t < 4; ++t) {
    const int r = wm + t * 16 + (lane & 15);
    offA[t] = r * 64 + (((lane >> 4) ^ ((r >> 1) & 3)) * 16);
    const int rn = wn + t * 16 + (lane & 15);
    offB[t] = rn * 64 + (((lane >> 4) ^ ((rn >> 1) & 3)) * 16);
  }

  f32x4 acc[4][4] = {};
  const char* smb = (const char*)sm;

  for (int k0 = 0; k0 < K; k0 += 32) {
    if (wave < 3) {
#pragma unroll
      for (int inst = 0; inst < 8; ++inst)
        async_cp16(src + goff[inst] + k0,
                   (unsigned short*)((char*)dst0 + inst * 1024));
    }
    __syncthreads();

    short8 ah[4], al[4], bh[4];
#pragma unroll
    for (int t = 0; t < 4; ++t) {
      ah[t] = *(const short8*)(smb + offA[t]);
      al[t] = *(const short8*)(smb + 8192 + offA[t]);
      bh[t] = *(const short8*)(smb + 16384 + offB[t]);
    }
#pragma unroll
    for (int t = 0; t < 4; ++t)
#pragma unroll
      for (int u = 0; u < 4; ++u) {
        acc[t][u] = __builtin_amdgcn_mfma_f32_16x16x32_bf16(ah[t], bh[u], acc[t][u], 0, 0, 0);
        acc[t][u] = __builtin_amdgcn_mfma_f32_16x16x32_bf16(al[t], bh[u], acc[t][u], 0, 0, 0);
      }
    __syncthreads();
  }

#pragma unroll
  for (int u = 0; u < 4; ++u) {
    const int col = n0 + wn + u * 16 + (lane & 15);
    const float bv = bias[col];
#pragma unroll
    for (int t = 0; t < 4; ++t) {
      const int row0 = m0 + wm + t * 16 + ((lane >> 4) << 2);
      if (MODE == 0) {
#pragma unroll
        for (int e = 0; e < 4; ++e)
          C[(size_t)(row0 + e) * N + col] = acc[t][u][e] + bv;
      } else {
        const int slot = col >> 10;   // 0=q,1=k,2=v (wave-uniform per tile)
        const int hd   = col & 1023;
        if (slot < 2) {
#pragma unroll
          for (int e = 0; e < 4; ++e) {
            unsigned short hh, ll;
            split1(acc[t][u][e] + bv, hh, ll);
            const size_t o = ((size_t)(row0 + e) * 2 + slot) * 1024 + hd;
            qk_h[o] = hh;
            qk_l[o] = ll;
          }
        } else {
          const int bb = row0 >> 11, l0 = row0 & 2047;
          ushort4 vh, vl;
          split1(acc[t][u][0] + bv, vh.x, vl.x);
          split1(acc[t][u][1] + bv, vh.y, vl.y);
          split1(acc[t][u][2] + bv, vh.z, vl.z);
          split1(acc[t][u][3] + bv, vh.w, vl.w);
          const size_t o = ((size_t)bb * 1024 + hd) * 2048 + l0;
          *(ushort4*)&vT_h[o] = vh;
          *(ushort4*)&vT_l[o] = vl;
        }
      }
    }
  }
}

// ---------------------------------------------------------------------------
// MFMA sliding-window attention. Block = (b, h, 32 queries), 4 waves.
// Phase 1: S = (Qh+Ql) @ Kh^T (2 products, K rounded to bf16), direct global
//          frag loads, C-layout scatter to fp32 LDS slab.
// Phase 2: softmax (reg-cached), write normalized P bf16 over the slab.
// Phase 3: O = P @ (Vh+Vl), P frags from LDS, V frags direct from vT global.
// ---------------------------------------------------------------------------
__global__ __launch_bounds__(256, 4) void attn_mfma(
    const unsigned short* __restrict__ qk_h,
    const unsigned short* __restrict__ qk_l,
    const unsigned short* __restrict__ vT_h,
    const unsigned short* __restrict__ vT_l,
    unsigned short* __restrict__ attn_h,
    unsigned short* __restrict__ attn_l) {
  __shared__ float Sf[TQ * SROW];   // 37376 B, P bf16 slab aliases this
  __shared__ float red[256];
  unsigned short* P = (unsigned short*)Sf;

  const int b   = blockIdx.z;
  const int h   = blockIdx.y;
  const int i0  = blockIdx.x * TQ;
  const int tid = threadIdx.x;
  const int wave = tid >> 6, lane = tid & 63;
  const int quad = lane >> 4, ln16 = lane & 15;
  const int jlo = i0 - HALF_;
  const int mt = wave >> 1;         // m-tile (0,1)

  // ---- phase 1: scores ----------------------------------------------------
  {
    short8 qh[2], ql[2];
    const size_t qbase =
        ((size_t)(b * L_ + i0 + mt * 16 + ln16) * 2 + 0) * 1024 + h * 64 + quad * 8;
    qh[0] = *(const short8*)&qk_h[qbase];
    qh[1] = *(const short8*)&qk_h[qbase + 32];
    ql[0] = *(const short8*)&qk_l[qbase];
    ql[1] = *(const short8*)&qk_l[qbase + 32];

    for (int c = 0; c < 9; ++c) {
      const int nt   = (wave & 1) + 2 * c;        // n-tile 0..17
      const int jabs = jlo + nt * 16 + ln16;
      const int jcl  = min(max(jabs, 0), L_ - 1);
      const size_t kbase =
          ((size_t)(b * L_ + jcl) * 2 + 1) * 1024 + h * 64 + quad * 8;
      const short8 kh0 = *(const short8*)&qk_h[kbase];
      const short8 kh1 = *(const short8*)&qk_h[kbase + 32];

      f32x4 acc = {};
      acc = __builtin_amdgcn_mfma_f32_16x16x32_bf16(qh[0], kh0, acc, 0, 0, 0);
      acc = __builtin_amdgcn_mfma_f32_16x16x32_bf16(ql[0], kh0, acc, 0, 0, 0);
      acc = __builtin_amdgcn_mfma_f32_16x16x32_bf16(qh[1], kh1, acc, 0, 0, 0);
      acc = __builtin_amdgcn_mfma_f32_16x16x32_bf16(ql[1], kh1, acc, 0, 0, 0);

      const int colj  = nt * 16 + ln16;
      const int rbase = mt * 16 + quad * 4;
#pragma unroll
      for (int e = 0; e < 4; ++e) {
        const int iabs = i0 + rbase + e;
        const bool ok = (jabs >= 0) && (jabs < L_) && (abs(iabs - jabs) <= HALF_);
        Sf[(rbase + e) * SROW + colj] = ok ? acc[e] * 0.125f : -INFINITY;
      }
    }
  }
  __syncthreads();

  // ---- phase 2: softmax ---------------------------------------------------
  {
    const int q = tid >> 3, lr = tid & 7;
    float v[36];
    const float* srow = &Sf[q * SROW + lr * 36];
    float lmax = -INFINITY;
#pragma unroll
    for (int u = 0; u < 9; ++u) {
      const float4 t4 = *(const float4*)&srow[u * 4];
      v[u * 4 + 0] = t4.x; v[u * 4 + 1] = t4.y;
      v[u * 4 + 2] = t4.z; v[u * 4 + 3] = t4.w;
      lmax = fmaxf(lmax, fmaxf(fmaxf(t4.x, t4.y), fmaxf(t4.z, t4.w)));
    }
    red[tid] = lmax;
    __syncthreads();
    float mrow = red[q * 8];
#pragma unroll
    for (int u = 1; u < 8; ++u) mrow = fmaxf(mrow, red[q * 8 + u]);
    float lsum = 0.f;
#pragma unroll
    for (int i = 0; i < 36; ++i) {
      v[i] = __expf(v[i] - mrow);
      lsum += v[i];
    }
    __syncthreads();
    red[tid] = lsum;
    __syncthreads();
    float tot = 0.f;
#pragma unroll
    for (int u = 0; u < 8; ++u) tot += red[q * 8 + u];
    const float rinv = 1.f / tot;
    unsigned short* prow = &P[q * PROW + lr * 36];
#pragma unroll
    for (int i = 0; i < 36; ++i) prow[i] = f2bf(v[i] * rinv);
  }
  __syncthreads();

  // ---- phase 3: O = P @ V -------------------------------------------------
  {
    const int dp = wave & 1;
    const char* pb = (const char*)P;
    f32x4 o[2] = {};
    for (int c = 0; c < 9; ++c) {
      const short8 pf =
          *(const short8*)(pb + (mt * 16 + ln16) * (PROW * 2) + c * 64 + quad * 16);
      int j0 = jlo + c * 32 + quad * 8;
      j0 = min(max(j0, 0), L_ - 8);
#pragma unroll
      for (int t = 0; t < 2; ++t) {
        const size_t vb =
            ((size_t)b * 1024 + h * 64 + dp * 32 + t * 16 + ln16) * 2048 + j0;
        o[t] = __builtin_amdgcn_mfma_f32_16x16x32_bf16(
            pf, *(const short8*)&vT_h[vb], o[t], 0, 0, 0);
        o[t] = __builtin_amdgcn_mfma_f32_16x16x32_bf16(
            pf, *(const short8*)&vT_l[vb], o[t], 0, 0, 0);
      }
    }
#pragma unroll
    for (int t = 0; t < 2; ++t) {
      const int col = h * 64 + dp * 32 + t * 16 + ln16;
#pragma unroll
      for (int e = 0; e < 4; ++e) {
        const int row = i0 + mt * 16 + quad * 4 + e;
        unsigned short hh, ll;
        split1(o[t][e], hh, ll);
        const size_t oo = (size_t)(b * L_ + row) * 1024 + col;
        attn_h[oo] = hh;
        attn_l[oo] = ll;
      }
    }
  }
}

// ---------------------------------------------------------------------------
extern "C" void kernel_launch(void* const* d_in, const int* in_sizes, int n_in,
                              void* d_out, int out_size, void* d_ws, size_t ws_size,
                              hipStream_t stream) {
  const float* x     = (const float*)d_in[0];
  const float* w_qkv = (const float*)d_in[1];
  const float* b_qkv = (const float*)d_in[2];
  const float* w_out = (const float*)d_in[3];
  const float* b_out = (const float*)d_in[4];
  float* out = (float*)d_out;

  const int M = B_ * L_;  // 4096

  // workspace layout (bytes):
  //   x_hi @0 (8MiB)        x_lo @8MiB        [dead after QKV gemm]
  //   wqkvT_hi @16MiB (6MiB)                  [dead after QKV gemm]
  //   qk_hi @28MiB (16MiB)  qk_lo @44MiB      [B,L,2,1024]
  //   vT_hi @60MiB (8MiB)   vT_lo @68MiB      [B,1024,L]
  // aliases over dead regions:
  //   attn_hi @0, attn_lo @8MiB;  woutT_hi @16MiB
  char* ws = (char*)d_ws;
  unsigned short* x_hi     = (unsigned short*)(ws + 0);
  unsigned short* x_lo     = (unsigned short*)(ws + 8388608);
  unsigned short* wqkvT_hi = (unsigned short*)(ws + 16777216);
  unsigned short* qk_hi    = (unsigned short*)(ws + 29360128);
  unsigned short* qk_lo    = (unsigned short*)(ws + 46137344);
  unsigned short* vT_hi    = (unsigned short*)(ws + 62914560);
  unsigned short* vT_lo    = (unsigned short*)(ws + 71303168);
  unsigned short* attn_hi  = (unsigned short*)(ws + 0);
  unsigned short* attn_lo  = (unsigned short*)(ws + 8388608);
  unsigned short* woutT_hi = (unsigned short*)(ws + 16777216);

  // 1) split x -> bf16 hi/lo
  split_rm<<<M * D_ / 1024, 256, 0, stream>>>(x, x_hi, x_lo);
  // 2) transpose+round w_qkv [D,3D] -> bf16 [3D,D]
  {
    dim3 g(3 * D_ / 32, D_ / 32);
    transpose_round<<<g, 256, 0, stream>>>(w_qkv, wqkvT_hi, 3 * D_, D_);
  }
  // 3) QKV projection -> qk (split bf16) + vT (split bf16, transposed)
  {
    dim3 g(3 * D_ / 128, M / 128);
    gemm_split<1><<<g, 256, 0, stream>>>(x_hi, x_lo, wqkvT_hi, b_qkv,
                                         nullptr, qk_hi, qk_lo, vT_hi, vT_lo,
                                         3 * D_, D_);
  }
  // 4) transpose+round w_out [D,D] -> bf16 [D,D] (aliases dead wqkvT)
  {
    dim3 g(D_ / 32, D_ / 32);
    transpose_round<<<g, 256, 0, stream>>>(w_out, woutT_hi, D_, D_);
  }
  // 5) MFMA banded attention -> attn split bf16 (aliases dead x)
  {
    dim3 g(L_ / TQ, H_, B_);
    attn_mfma<<<g, 256, 0, stream>>>(qk_hi, qk_lo, vT_hi, vT_lo, attn_hi, attn_lo);
  }
  // 6) output projection -> fp32 d_out
  {
    dim3 g(D_ / 128, M / 128);
    gemm_split<0><<<g, 256, 0, stream>>>(attn_hi, attn_lo, woutT_hi, b_out,
                                         out, nullptr, nullptr, nullptr,
                                         nullptr, D_, D_);
  }
}